// Round 26
// baseline (556.093 us; speedup 1.0000x reference)
//
#include <hip/hip_runtime.h>
#include <hip/hip_bf16.h>

typedef __bf16 bf16;
typedef __bf16 bf16x8 __attribute__((ext_vector_type(8)));
typedef float f32x4 __attribute__((ext_vector_type(4)));
typedef unsigned char u8;
typedef unsigned int u32;
typedef unsigned short u16;
typedef u16 ushort4v __attribute__((ext_vector_type(4)));
typedef u32 u32x4 __attribute__((ext_vector_type(4)));

#define B_ 4
#define T_ 1024
#define NX_ 1024
#define NH_ 16
#define HD_ 64

__device__ __forceinline__ void gld16(const void* g, void* l) {
  __builtin_amdgcn_global_load_lds((const __attribute__((address_space(1))) void*)g,
                                   (__attribute__((address_space(3))) void*)l, 16, 0, 0);
}

// ---------- prep: contiguous fp32 -> bf16 ----------
__global__ __launch_bounds__(256) void k_cvt(const float* __restrict__ in, bf16* __restrict__ out, int n) {
  int i = (blockIdx.x * 256 + threadIdx.x) * 4;
  if (i + 3 < n) {
    float4 v = *(const float4*)(in + i);
    out[i] = (bf16)v.x; out[i + 1] = (bf16)v.y; out[i + 2] = (bf16)v.z; out[i + 3] = (bf16)v.w;
  }
}

// ---------- prep: (K,N) f32 -> (N,K) bf16 transpose ----------
__global__ __launch_bounds__(256) void k_transpose(const float* __restrict__ in, bf16* __restrict__ out, int K, int N) {
  __shared__ float tile[64][65];
  int n0 = blockIdx.x * 64, k0 = blockIdx.y * 64;
  for (int i = threadIdx.x; i < 4096; i += 256) {
    int r = i >> 6, c = i & 63;
    tile[r][c] = in[(size_t)(k0 + r) * N + n0 + c];
  }
  __syncthreads();
  for (int i = threadIdx.x; i < 4096; i += 256) {
    int r = i >> 6, c = i & 63;
    out[(size_t)(n0 + r) * K + k0 + c] = (bf16)tile[c][r];
  }
}

// ---------- pack int32 ids -> u8 ([t][s] natural layout; rel 4MB then rel_ids 1MB) ----------
__global__ __launch_bounds__(256) void k_pack(const int* __restrict__ rel, const int* __restrict__ rel_ids,
                                              u8* __restrict__ dst8) {
  int i = (blockIdx.x * 256 + threadIdx.x) * 4;
  const int* src = (i < 4194304) ? (rel + i) : (rel_ids + (i - 4194304));
  int4 v = *(const int4*)src;
  uchar4 o = {(u8)v.x, (u8)v.y, (u8)v.z, (u8)v.w};
  *(uchar4*)(dst8 + i) = o;
}

// ---------- rel_values^T as bf16 (64d x 64rr) for epilogue MFMA ----------
__global__ __launch_bounds__(256) void k_rvt(const float* __restrict__ rel_values, bf16* __restrict__ rvT) {
  int d = threadIdx.x >> 2, seg = threadIdx.x & 3;
  for (int i = 0; i < 16; ++i) {
    int rr = seg * 16 + i;
    rvT[d * 64 + rr] = (bf16)rel_values[rr * 64 + d];
  }
}

// ---------- 128x128 bf16 MFMA GEMM, BK=32, double-buffered global_load_lds ----------
template <int EPI>
__global__ __launch_bounds__(256) void k_gemm(
    const bf16* __restrict__ A, const bf16* __restrict__ BT, const float* __restrict__ bias,
    float* __restrict__ outF, bf16* __restrict__ qg, bf16* __restrict__ kg, bf16* __restrict__ vtg,
    int M, int N, int K) {
  __shared__ __align__(16) bf16 Ab[2][128 * 32];
  __shared__ __align__(16) bf16 Bb[2][128 * 32];
  int tid = threadIdx.x, lane = tid & 63, w = tid >> 6;
  int wm = w >> 1, wn = w & 1;
  int m0 = blockIdx.y * 128, n0 = blockIdx.x * 128;
  int sl = lane >> 4, lr = lane & 15;
  f32x4 acc[4][4] = {};
  int NKt = K >> 5;

  auto stage = [&](int kt, int bidx) {
    const bf16* Ag = A + (size_t)m0 * K + kt * 32;
    const bf16* Bg = BT + (size_t)n0 * K + kt * 32;
#pragma unroll
    for (int j = 0; j < 2; ++j) {
      int c = w * 128 + j * 64 + lane;
      int row = c >> 2, slot = c & 3;
      int ss = slot ^ ((row >> 1) & 3);
      gld16(Ag + (size_t)row * K + ss * 8, &Ab[bidx][(w * 128 + j * 64) * 8]);
      gld16(Bg + (size_t)row * K + ss * 8, &Bb[bidx][(w * 128 + j * 64) * 8]);
    }
  };
  stage(0, 0);
  for (int kt = 0; kt < NKt; ++kt) {
    int bidx = kt & 1;
    __syncthreads();
    if (kt + 1 < NKt) stage(kt + 1, bidx ^ 1);
    bf16x8 af[4], bfv[4];
#pragma unroll
    for (int mi = 0; mi < 4; ++mi) {
      int row = wm * 64 + mi * 16 + lr;
      af[mi] = *(const bf16x8*)&Ab[bidx][row * 32 + ((sl ^ ((row >> 1) & 3)) * 8)];
    }
#pragma unroll
    for (int ni = 0; ni < 4; ++ni) {
      int row = wn * 64 + ni * 16 + lr;
      bfv[ni] = *(const bf16x8*)&Bb[bidx][row * 32 + ((sl ^ ((row >> 1) & 3)) * 8)];
    }
#pragma unroll
    for (int mi = 0; mi < 4; ++mi)
#pragma unroll
      for (int ni = 0; ni < 4; ++ni)
        acc[mi][ni] = __builtin_amdgcn_mfma_f32_16x16x32_bf16(af[mi], bfv[ni], acc[mi][ni], 0, 0, 0);
  }
#pragma unroll
  for (int ni = 0; ni < 4; ++ni) {
    int n = n0 + wn * 64 + ni * 16 + lr;
    float bv = bias[n];
#pragma unroll
    for (int mi = 0; mi < 4; ++mi) {
      int mb = m0 + wm * 64 + mi * 16 + sl * 4;
#pragma unroll
      for (int r = 0; r < 4; ++r) {
        float v = acc[mi][ni][r] + bv;
        int m = mb + r;
        if (EPI == 0) {
          int region = n >> 10, hh = (n & 1023) >> 6, d = n & 63;
          int bb = m >> 10, t = m & 1023;
          int bh = bb * NH_ + hh;
          if (region == 0)      qg[((size_t)bh * T_ + t) * HD_ + d] = (bf16)v;
          else if (region == 1) kg[((size_t)bh * T_ + t) * HD_ + d] = (bf16)v;
          else                  vtg[((size_t)bh * HD_ + d) * T_ + t] = (bf16)v;
        } else {
          outF[(size_t)m * N + n] = v;
        }
      }
    }
  }
}

// ---------- wave-paired fused attention (R13-validated, plain loads) + named probes ----------
// V: 0 full | 1 no-atomics | 2 no-shuffle/PV | 3 stage-only | 4 no-exp
// NO inline-asm loads (R19/R24/R25 aborts traced to hand-asm async loads under regalloc
// perturbation); compiler schedules loads, which measured identical (R13: 192.6us = R16: 190us).

#define KEEPV(x) asm volatile("" :: "v"(x))

#define LOADKV(s0v, P)                                                           \
  do {                                                                           \
    int s0_ = (s0v);                                                             \
    P##k00 = *(const bf16x8*)(klane + (size_t)s0_ * HD_);                        \
    P##k01 = *(const bf16x8*)(klane + (size_t)s0_ * HD_ + 32);                   \
    P##k10 = *(const bf16x8*)(klane + (size_t)(s0_ + 16) * HD_);                 \
    P##k11 = *(const bf16x8*)(klane + (size_t)(s0_ + 16) * HD_ + 32);            \
    P##v0 = *(const bf16x8*)(vlane + s0_);                                       \
    P##v1 = *(const bf16x8*)(vlane + 16 * T_ + s0_);                             \
    P##v2 = *(const bf16x8*)(vlane + 32 * T_ + s0_);                             \
    P##v3 = *(const bf16x8*)(vlane + 48 * T_ + s0_);                             \
    P##rid0 = *(const u32*)(ridlane + s0_);                                      \
    P##rid1 = *(const u32*)(ridlane + s0_ + 16);                                 \
    P##iid0 = *(const u32*)(iidlane + s0_);                                      \
    P##iid1 = *(const u32*)(iidlane + s0_ + 16);                                 \
  } while (0)

#define KEEPALL(P)                                                               \
  do {                                                                           \
    KEEPV(P##k00); KEEPV(P##k01); KEEPV(P##k10); KEEPV(P##k11);                  \
    KEEPV(P##v0); KEEPV(P##v1); KEEPV(P##v2); KEEPV(P##v3);                      \
    KEEPV(P##rid0); KEEPV(P##rid1); KEEPV(P##iid0); KEEPV(P##iid1);              \
  } while (0)

#define COMPUTE(s0v, P)                                                          \
  do {                                                                           \
    int s0_ = (s0v);                                                             \
    f32x4 S0_ = {}, S1_ = {};                                                    \
    S0_ = __builtin_amdgcn_mfma_f32_16x16x32_bf16(P##k00, qf0, S0_, 0, 0, 0);    \
    S0_ = __builtin_amdgcn_mfma_f32_16x16x32_bf16(P##k01, qf1, S0_, 0, 0, 0);    \
    S1_ = __builtin_amdgcn_mfma_f32_16x16x32_bf16(P##k10, qf0, S1_, 0, 0, 0);    \
    S1_ = __builtin_amdgcn_mfma_f32_16x16x32_bf16(P##k11, qf1, S1_, 0, 0, 0);    \
    u16 pb_[8];                                                                  \
    {                                                                            \
      int sbase_ = s0_ + sl * 4;                                                 \
      _Pragma("unroll") for (int r = 0; r < 4; ++r) {                            \
        float e;                                                                 \
        if constexpr (V == 4) e = (sbase_ + r <= tglob) ? S0_[r] * 0.125f * tab[(P##rid0 >> (8 * r)) & 63] : 0.f; \
        else e = (sbase_ + r <= tglob) ? __expf(S0_[r] * 0.125f) * tab[(P##rid0 >> (8 * r)) & 63] : 0.f; \
        lsum += e;                                                               \
        bf16 eb = (bf16)e;                                                       \
        pb_[r] = *(u16*)&eb;                                                     \
        if constexpr (V != 1)                                                    \
          if (e != 0.f) atomicAdd(&prel[lr * 68 + ((P##iid0 >> (8 * r)) & 63)], e); \
      }                                                                          \
      sbase_ += 16;                                                              \
      _Pragma("unroll") for (int r = 0; r < 4; ++r) {                            \
        float e;                                                                 \
        if constexpr (V == 4) e = (sbase_ + r <= tglob) ? S1_[r] * 0.125f * tab[(P##rid1 >> (8 * r)) & 63] : 0.f; \
        else e = (sbase_ + r <= tglob) ? __expf(S1_[r] * 0.125f) * tab[(P##rid1 >> (8 * r)) & 63] : 0.f; \
        lsum += e;                                                               \
        bf16 eb = (bf16)e;                                                       \
        pb_[4 + r] = *(u16*)&eb;                                                 \
        if constexpr (V != 1)                                                    \
          if (e != 0.f) atomicAdd(&prel[lr * 68 + ((P##iid1 >> (8 * r)) & 63)], e); \
      }                                                                          \
    }                                                                            \
    u32 a0_ = (u32)pb_[0] | ((u32)pb_[1] << 16);                                 \
    u32 b0_ = (u32)pb_[2] | ((u32)pb_[3] << 16);                                 \
    u32 a1_ = (u32)pb_[4] | ((u32)pb_[5] << 16);                                 \
    u32 b1_ = (u32)pb_[6] | ((u32)pb_[7] << 16);                                 \
    if constexpr (V == 2) {                                                      \
      KEEPV(a0_); KEEPV(b0_); KEEPV(a1_); KEEPV(b1_);                            \
      KEEPV(P##v0); KEEPV(P##v1); KEEPV(P##v2); KEEPV(P##v3);                    \
    } else {                                                                     \
      int srcA_ = lr + (((sl & 1) * 2) << 4);                                    \
      int srcB_ = srcA_ + 16;                                                    \
      u32 taA0_ = (u32)__shfl((int)a0_, srcA_), taA1_ = (u32)__shfl((int)a1_, srcA_); \
      u32 tbA0_ = (u32)__shfl((int)b0_, srcA_), tbA1_ = (u32)__shfl((int)b1_, srcA_); \
      u32 taB0_ = (u32)__shfl((int)a0_, srcB_), taB1_ = (u32)__shfl((int)a1_, srcB_); \
      u32 tbB0_ = (u32)__shfl((int)b0_, srcB_), tbB1_ = (u32)__shfl((int)b1_, srcB_); \
      bool hi_ = (sl & 2) != 0;                                                  \
      u16 pw_[8];                                                                \
      *(u32*)&pw_[0] = hi_ ? taA1_ : taA0_;                                      \
      *(u32*)&pw_[2] = hi_ ? tbA1_ : tbA0_;                                      \
      *(u32*)&pw_[4] = hi_ ? taB1_ : taB0_;                                      \
      *(u32*)&pw_[6] = hi_ ? tbB1_ : tbB0_;                                      \
      bf16x8 pfrag_ = *(bf16x8*)&pw_[0];                                         \
      acc[0] = __builtin_amdgcn_mfma_f32_16x16x32_bf16(P##v0, pfrag_, acc[0], 0, 0, 0); \
      acc[1] = __builtin_amdgcn_mfma_f32_16x16x32_bf16(P##v1, pfrag_, acc[1], 0, 0, 0); \
      acc[2] = __builtin_amdgcn_mfma_f32_16x16x32_bf16(P##v2, pfrag_, acc[2], 0, 0, 0); \
      acc[3] = __builtin_amdgcn_mfma_f32_16x16x32_bf16(P##v3, pfrag_, acc[3], 0, 0, 0); \
    }                                                                            \
  } while (0)

template <int V>
__device__ __forceinline__ void attn_body(
    const bf16* __restrict__ qg, const bf16* __restrict__ kg, const bf16* __restrict__ vtg,
    const u8* __restrict__ rel8, const float* __restrict__ rel_weights,
    const u8* __restrict__ relid8, const bf16* __restrict__ rvT,
    bf16* __restrict__ ret) {
  __shared__ float prelBase[4 * 1088];
  __shared__ float tabBase[4 * 64];

  int bid = blockIdx.x;
  int x = bid & 7, j = bid >> 3;
  int b = x >> 1;
  int h = (x & 1) + ((j >> 3) << 1);
  int q = j & 7;
  int w = threadIdx.x >> 6;
  int lane = threadIdx.x & 63;
  int lr = lane & 15, sl = lane >> 4;
  int p = q * 4 + w;
  int bh = b * NH_ + h;

  float* prel = prelBase + w * 1088;
  float* tab = tabBase + w * 64;
  tab[lane] = __expf(rel_weights[lane * NH_ + h]);

  const u8* relbase = rel8 + (size_t)b * T_ * T_;

#pragma unroll
  for (int side = 0; side < 2; ++side) {
    int tt = side ? p : 63 - p;
    int t0 = tt * 16;
    int tglob = t0 + lr;

#pragma unroll
    for (int i = 0; i < 17; ++i) prel[i * 64 + lane] = 0.f;

    const bf16* qrow = qg + ((size_t)bh * T_ + t0 + lr) * HD_;
    const bf16* klane = kg + ((size_t)bh * T_ + lr) * HD_ + sl * 8;
    const bf16* vlane = vtg + ((size_t)bh * HD_ + lr) * T_ + sl * 8;
    const u8* ridlane = relbase + (size_t)(t0 + lr) * T_ + sl * 4;
    const u8* iidlane = relid8 + (size_t)(t0 + lr) * T_ + sl * 4;

    f32x4 acc[4] = {};
    float lsum = 0.f;

    bf16x8 qf0 = *(const bf16x8*)(qrow + sl * 8);
    bf16x8 qf1 = *(const bf16x8*)(qrow + 32 + sl * 8);

    bf16x8 ak00, ak01, ak10, ak11, av0, av1, av2, av3;
    u32 arid0, arid1, aiid0, aiid1;
    bf16x8 bk00, bk01, bk10, bk11, bv0, bv1, bv2, bv3;
    u32 brid0, brid1, biid0, biid1;

    int nst = (tt >> 1) + 1;
    LOADKV(0, a);
    for (int st = 0; st < nst; st += 2) {
      if (st + 1 < nst) LOADKV((st + 1) * 32, b);
      if constexpr (V == 3) KEEPALL(a); else COMPUTE(st * 32, a);
      if (st + 1 < nst) {
        if (st + 2 < nst) LOADKV((st + 2) * 32, a);
        if constexpr (V == 3) KEEPALL(b); else COMPUTE((st + 1) * 32, b);
      }
    }

    if constexpr (V != 0) {
      KEEPV(lsum);
#pragma unroll
      for (int ni = 0; ni < 4; ++ni)
#pragma unroll
        for (int r = 0; r < 4; ++r) KEEPV(acc[ni][r]);
      continue;
    }

    // ---- per-strip epilogue (V0 only) ----
    float v = lsum;
    v += __shfl_xor(v, 16);
    v += __shfl_xor(v, 32);
    float inv = 1.f / v;

#pragma unroll
    for (int kc = 0; kc < 2; ++kc) {
      f32x4 pA = *(const f32x4*)&prel[lr * 68 + kc * 32 + sl * 8];
      f32x4 pB = *(const f32x4*)&prel[lr * 68 + kc * 32 + sl * 8 + 4];
      u16 pb[8];
#pragma unroll
      for (int jj = 0; jj < 4; ++jj) { bf16 xx = (bf16)pA[jj]; pb[jj] = *(u16*)&xx; }
#pragma unroll
      for (int jj = 0; jj < 4; ++jj) { bf16 xx = (bf16)pB[jj]; pb[4 + jj] = *(u16*)&xx; }
      bf16x8 pfrag = *(bf16x8*)&pb[0];
#pragma unroll
      for (int ni = 0; ni < 4; ++ni) {
        bf16x8 af = *(const bf16x8*)(rvT + (size_t)(ni * 16 + lr) * 64 + kc * 32 + sl * 8);
        acc[ni] = __builtin_amdgcn_mfma_f32_16x16x32_bf16(af, pfrag, acc[ni], 0, 0, 0);
      }
    }

    bf16* rp = ret + ((size_t)(b * T_ + t0 + lr)) * NX_ + h * HD_ + sl * 4;
#pragma unroll
    for (int ni = 0; ni < 4; ++ni) {
      ushort4v ov;
#pragma unroll
      for (int r = 0; r < 4; ++r) {
        bf16 xx = (bf16)(acc[ni][r] * inv);
        ov[r] = *(u16*)&xx;
      }
      *(ushort4v*)(rp + ni * 16) = ov;
    }
    __syncthreads();  // prel reuse barrier between sides (all waves in lockstep phases)
  }
}

#define ATTN_ARGS const bf16* qg, const bf16* kg, const bf16* vtg, const u8* rel8, \
                  const float* rw, const u8* relid8, const bf16* rvT, bf16* ret
__global__ __launch_bounds__(256, 2) void k_attn(ATTN_ARGS) { attn_body<0>(qg, kg, vtg, rel8, rw, relid8, rvT, ret); }
__global__ __launch_bounds__(256, 2) void ka_p1(ATTN_ARGS)  { attn_body<1>(qg, kg, vtg, rel8, rw, relid8, rvT, ret); }
__global__ __launch_bounds__(256, 2) void ka_p2(ATTN_ARGS)  { attn_body<2>(qg, kg, vtg, rel8, rw, relid8, rvT, ret); }
__global__ __launch_bounds__(256, 2) void ka_p3(ATTN_ARGS)  { attn_body<3>(qg, kg, vtg, rel8, rw, relid8, rvT, ret); }
__global__ __launch_bounds__(256, 2) void ka_p4(ATTN_ARGS)  { attn_body<4>(qg, kg, vtg, rel8, rw, relid8, rvT, ret); }

extern "C" void kernel_launch(void* const* d_in, const int* in_sizes, int n_in,
                              void* d_out, int out_size, void* d_ws, size_t ws_size,
                              hipStream_t stream) {
  const float* x = (const float*)d_in[0];
  const int* rel = (const int*)d_in[1];
  const float* w_attn = (const float*)d_in[2];
  const float* b_attn = (const float*)d_in[3];
  const float* w_proj = (const float*)d_in[4];
  const float* b_proj = (const float*)d_in[5];
  const float* rel_weights = (const float*)d_in[6];
  const float* rel_values = (const float*)d_in[7];
  const int* rel_ids = (const int*)d_in[8];
  float* out = (float*)d_out;

  char* ws = (char*)d_ws;
  bf16* xb  = (bf16*)(ws);
  bf16* wTa = (bf16*)(ws + 8388608);
  bf16* wTp = (bf16*)(ws + 14680064);
  bf16* qg  = (bf16*)(ws + 16777216);
  bf16* kg  = (bf16*)(ws + 25165824);
  bf16* vtg = (bf16*)(ws + 33554432);
  bf16* ret = (bf16*)(ws + 41943040);
  u8* rel8   = (u8*)(ws);
  u8* relid8 = (u8*)(ws + 4194304);
  bf16* rvT  = (bf16*)(ws + 5242880);

  k_cvt<<<4096, 256, 0, stream>>>(x, xb, 4194304);
  k_transpose<<<dim3(48, 16), 256, 0, stream>>>(w_attn, wTa, 1024, 3072);
  k_transpose<<<dim3(16, 16), 256, 0, stream>>>(w_proj, wTp, 1024, 1024);
  k_gemm<0><<<dim3(24, 32), 256, 0, stream>>>(xb, wTa, b_attn, nullptr, qg, kg, vtg, 4096, 3072, 1024);
  k_pack<<<5120, 256, 0, stream>>>(rel, rel_ids, rel8);
  k_rvt<<<1, 256, 0, stream>>>(rel_values, rvT);
  k_attn<<<512, 256, 0, stream>>>(qg, kg, vtg, rel8, rel_weights, relid8, rvT, ret);
  k_gemm<1><<<dim3(8, 32), 256, 0, stream>>>(ret, wTp, b_proj, out, nullptr, nullptr, nullptr, 4096, 1024, 1024);
  // ---- named ablation probes (half grid; durations read from rocprof; dropped next round) ----
  ka_p1<<<256, 256, 0, stream>>>(qg, kg, vtg, rel8, rel_weights, relid8, rvT, ret);
  ka_p2<<<256, 256, 0, stream>>>(qg, kg, vtg, rel8, rel_weights, relid8, rvT, ret);
  ka_p3<<<256, 256, 0, stream>>>(qg, kg, vtg, rel8, rel_weights, relid8, rvT, ret);
  ka_p4<<<256, 256, 0, stream>>>(qg, kg, vtg, rel8, rel_weights, relid8, rvT, ret);
}